// Round 6
// baseline (118.071 us; speedup 1.0000x reference)
//
#include <hip/hip_runtime.h>
#include <hip/hip_bf16.h>
#include <stdint.h>

// MetricLearningLoss: N=4096 points, D=1024, fp32 inputs, int labels.
// loss = sum_{i<j} [ same: -coeff*log(a)+0.5a ; diff: coeff*log(b)-0.5b ]
// R5 (resubmit; R5 bench was a broker timeout): barrier-free loss kernel.
// MX-fp8 gram fragments loaded DIRECTLY from global (4MB matrix is
// L2-resident) into MFMA registers - no LDS, no __syncthreads, counted
// vmcnt from the compiler, full K unroll for software pipelining.
// d_out zeroing folded into prep. T1 XCD swizzle.

#define NPTS 4096
#define DIM  1024
#define TILE 128
#define BK   128                      // fp8 bytes (= elems) per k-step
#define KSTEPS (DIM / BK)             // 8
#define NT   (NPTS / TILE)            // 32
#define NPAIR (NT * (NT + 1) / 2)     // 528 = 8 * 66
#define THREADS 256

typedef __attribute__((ext_vector_type(4))) float f32x4;
typedef __attribute__((ext_vector_type(4))) int   i32x4;
typedef __attribute__((ext_vector_type(8))) int   i32x8;

// Kernel 1: fp32 -> fp8 e4m3 (OCP, native gfx950 cvt) + per-row sum of
// squares in fp32 (exact norms; only the gram term is quantized).
// Also zeroes the output scalar (replaces a separate memset dispatch).
__global__ __launch_bounds__(256) void prep_kernel(const float* __restrict__ X,
                                                   uint8_t* __restrict__ Xf8,
                                                   float* __restrict__ sq,
                                                   float* __restrict__ out) {
    const int row = blockIdx.x;
    const int t = threadIdx.x;
    if (row == 0 && t == 0) out[0] = 0.0f;   // runs before loss_kernel (stream order)
    const float4 v = reinterpret_cast<const float4*>(X + (size_t)row * DIM)[t];
    float s = v.x * v.x + v.y * v.y + v.z * v.z + v.w * v.w;
    int w = __builtin_amdgcn_cvt_pk_fp8_f32(v.x, v.y, 0, false);
    w = __builtin_amdgcn_cvt_pk_fp8_f32(v.z, v.w, w, true);
    reinterpret_cast<int*>(Xf8 + (size_t)row * DIM)[t] = w;
#pragma unroll
    for (int off = 32; off > 0; off >>= 1) s += __shfl_down(s, off);
    __shared__ float ws[4];
    const int lane = t & 63, wv = t >> 6;
    if (lane == 0) ws[wv] = s;
    __syncthreads();
    if (t == 0) sq[row] = ws[0] + ws[1] + ws[2] + ws[3];
}

// Kernel 2: per upper-triangular 128x128 tile pair (ti<=tj): gram via
// MX-fp8 MFMA (scales = 1.0) with register-direct operand loads,
// fused loss epilogue, block reduce, atomicAdd. No LDS, no barriers
// in the main loop.
__global__ __launch_bounds__(THREADS, 2) void loss_kernel(const uint8_t* __restrict__ Xf8,
                                                          const float* __restrict__ sq,
                                                          const int* __restrict__ labels,
                                                          float* __restrict__ out) {
    __shared__ float bsum[4];

    // T1: bijective XCD swizzle (528 % 8 == 0).
    const int b0 = blockIdx.x;
    const int b = (b0 & 7) * (NPAIR / 8) + (b0 >> 3);

    // decode upper-triangular (ti, tj), ti <= tj
    int ti = 0, rem = b;
    while (rem >= NT - ti) { rem -= NT - ti; ++ti; }
    const int tj = ti + rem;

    const int t = threadIdx.x;
    const int lane = t & 63;
    const int wave = t >> 6;      // 0..3
    const int wr = wave >> 1;     // 0..1 : 64-row band of A
    const int wc = wave & 1;      // 0..1 : 64-col band of B
    const int fr = lane & 15;     // fragment row (A) / col (B)
    const int kg = lane >> 4;     // k-group: lane covers bytes [kg*32, kg*32+32)

    // Diagonal blocks: wave (1,0) fully below diagonal -> all outputs masked.
    const bool skipw = (ti == tj) && (wr == 1) && (wc == 0);

    f32x4 acc[4][4] = {};

    if (!skipw) {
        // Per-fragment global base pointers (lane-resolved): the MFMA
        // A/B operand for 16x16x128 is row (band + frag*16 + fr), k-bytes
        // [kg*32, kg*32+32) -- two dwordx4 loads. Same mapping for A and B,
        // so any internal k-permutation cancels in the gram (verified R4).
        const uint8_t* Ap[4];
        const uint8_t* Bp[4];
#pragma unroll
        for (int m = 0; m < 4; ++m)
            Ap[m] = Xf8 + (size_t)(ti * TILE + wr * 64 + m * 16 + fr) * DIM + kg * 32;
#pragma unroll
        for (int n = 0; n < 4; ++n)
            Bp[n] = Xf8 + (size_t)(tj * TILE + wc * 64 + n * 16 + fr) * DIM + kg * 32;

#pragma unroll
        for (int kt = 0; kt < KSTEPS; ++kt) {
            const int ko = kt * BK;
            i32x8 af[4], bv[4];
#pragma unroll
            for (int m = 0; m < 4; ++m) {
                const i32x4 lo = *(const i32x4*)(Ap[m] + ko);
                const i32x4 hi = *(const i32x4*)(Ap[m] + ko + 16);
                af[m][0] = lo[0]; af[m][1] = lo[1]; af[m][2] = lo[2]; af[m][3] = lo[3];
                af[m][4] = hi[0]; af[m][5] = hi[1]; af[m][6] = hi[2]; af[m][7] = hi[3];
            }
#pragma unroll
            for (int n = 0; n < 4; ++n) {
                const i32x4 lo = *(const i32x4*)(Bp[n] + ko);
                const i32x4 hi = *(const i32x4*)(Bp[n] + ko + 16);
                bv[n][0] = lo[0]; bv[n][1] = lo[1]; bv[n][2] = lo[2]; bv[n][3] = lo[3];
                bv[n][4] = hi[0]; bv[n][5] = hi[1]; bv[n][6] = hi[2]; bv[n][7] = hi[3];
            }
#pragma unroll
            for (int m = 0; m < 4; ++m)
#pragma unroll
                for (int n = 0; n < 4; ++n)
                    acc[m][n] = __builtin_amdgcn_mfma_scale_f32_16x16x128_f8f6f4(
                        af[m], bv[n], acc[m][n],
                        0 /*A=fp8*/, 0 /*B=fp8*/,
                        0, 0x7f7f7f7f,   // scale A = 2^0
                        0, 0x7f7f7f7f);  // scale B = 2^0
        }
    }

    // epilogue: C/D layout col = lane&15 (=fr), row = kg*4 + q  [m89/m91;
    // shape-determined, dtype-independent per m121-m128]
    int gi[16]; float sqi[16]; int li[16];
#pragma unroll
    for (int m = 0; m < 4; ++m)
#pragma unroll
        for (int q = 0; q < 4; ++q) {
            const int i = ti * TILE + wr * 64 + m * 16 + kg * 4 + q;
            gi[m * 4 + q] = i;
            sqi[m * 4 + q] = sq[i];
            li[m * 4 + q] = labels[i];
        }
    int gj[4]; float sqj[4]; int lj[4];
#pragma unroll
    for (int n = 0; n < 4; ++n) {
        const int j = tj * TILE + wc * 64 + n * 16 + fr;
        gj[n] = j;
        sqj[n] = sq[j];
        lj[n] = labels[j];
    }

    const float coeff = 2047.0f;                        // N/2 - 1
    const float inva = 1.0f / (2.0f * 4096.0f * 0.04f); // 1/327.68
    const float invb = 1.0f / (2.0f * 4096.0f);         // 1/8192
    const float lc1 = -5.792037522411088f;              // ln(inva)
    const float lc2 = -9.010913347279289f;              // ln(invb)
    const bool diag = (ti == tj);

    float lsum = 0.0f;
#pragma unroll
    for (int m = 0; m < 4; ++m)
#pragma unroll
        for (int n = 0; n < 4; ++n)
#pragma unroll
            for (int q = 0; q < 4; ++q) {
                const int ii = m * 4 + q;
                const float g = acc[m][n][q];
                float d2 = sqi[ii] + sqj[n] - 2.0f * g;
                d2 = fmaxf(d2, 1e-12f);
                const bool same = (li[ii] == lj[n]);
                const float inv = same ? inva : invb;
                const float lc  = same ? lc1 : lc2;
                const float sgn = same ? -1.0f : 1.0f;
                const float p = sgn * (coeff * (__logf(d2) + lc) - 0.5f * d2 * inv);
                const bool inc = diag ? (gi[ii] < gj[n]) : true;
                lsum += inc ? p : 0.0f;
            }

    // block reduce + one atomic per block
#pragma unroll
    for (int off = 32; off > 0; off >>= 1) lsum += __shfl_down(lsum, off);
    if (lane == 0) bsum[wave] = lsum;
    __syncthreads();
    if (t == 0) atomicAdd(out, bsum[0] + bsum[1] + bsum[2] + bsum[3]);
}

extern "C" void kernel_launch(void* const* d_in, const int* in_sizes, int n_in,
                              void* d_out, int out_size, void* d_ws, size_t ws_size,
                              hipStream_t stream) {
    const float* X = (const float*)d_in[0];
    const int* labels = (const int*)d_in[1];
    float* out = (float*)d_out;
    uint8_t* Xf8 = (uint8_t*)d_ws;                                  // 4 MB fp8
    float* sq = (float*)((char*)d_ws + (size_t)NPTS * DIM);         // 16 KB

    prep_kernel<<<NPTS, 256, 0, stream>>>(X, Xf8, sq, out);
    loss_kernel<<<NPAIR, THREADS, 0, stream>>>(Xf8, sq, labels, out);
}

// Round 9
// 103.293 us; speedup vs baseline: 1.1431x; 1.1431x over previous
//
#include <hip/hip_runtime.h>
#include <hip/hip_bf16.h>
#include <stdint.h>

// MetricLearningLoss: N=4096 points, D=1024, fp32 inputs, int labels.
// loss = sum_{i<j} [ same: -coeff*log(a)+0.5a ; diff: coeff*log(b)-0.5b ]
// R7 resubmit #2 (R7/R8 benches were broker timeouts): TLP attack.
// 64x64 tiles -> 2080 blocks (8.1/CU), 32KB LDS/block -> 5 blocks/CU
// resident (20 waves/CU) so stage+barrier stalls of one block hide under
// four others (m114). MX-fp8 (e4m3, unit scales) K=128 MFMA, dbuf
// prefetch, XOR swizzle via pre-swizzled source, diag-wave skip,
// T1 XCD swizzle, fused log epilogue.

#define NPTS 4096
#define DIM  1024
#define TILE 64
#define BK   128                      // fp8 bytes (= elems) per k-step
#define KSTEPS (DIM / BK)             // 8
#define NT   (NPTS / TILE)            // 64
#define NPAIR (NT * (NT + 1) / 2)     // 2080 = 8 * 260
#define THREADS 256

typedef __attribute__((ext_vector_type(4))) float f32x4;
typedef __attribute__((ext_vector_type(4))) int   i32x4;
typedef __attribute__((ext_vector_type(8))) int   i32x8;

__device__ __forceinline__ void gload_lds16(const void* g, void* l) {
    __builtin_amdgcn_global_load_lds(
        (const __attribute__((address_space(1))) void*)g,
        (__attribute__((address_space(3))) void*)l, 16, 0, 0);
}

// Kernel 1: fp32 -> fp8 e4m3 (OCP, native gfx950 cvt) + per-row sum of
// squares in fp32 (exact norms; only the gram term is quantized).
// Also zeroes the output scalar (replaces a separate memset dispatch).
__global__ __launch_bounds__(256) void prep_kernel(const float* __restrict__ X,
                                                   uint8_t* __restrict__ Xf8,
                                                   float* __restrict__ sq,
                                                   float* __restrict__ out) {
    const int row = blockIdx.x;
    const int t = threadIdx.x;
    if (row == 0 && t == 0) out[0] = 0.0f;   // stream-ordered before loss_kernel
    const float4 v = reinterpret_cast<const float4*>(X + (size_t)row * DIM)[t];
    float s = v.x * v.x + v.y * v.y + v.z * v.z + v.w * v.w;
    int w = __builtin_amdgcn_cvt_pk_fp8_f32(v.x, v.y, 0, false);
    w = __builtin_amdgcn_cvt_pk_fp8_f32(v.z, v.w, w, true);
    reinterpret_cast<int*>(Xf8 + (size_t)row * DIM)[t] = w;
#pragma unroll
    for (int off = 32; off > 0; off >>= 1) s += __shfl_down(s, off);
    __shared__ float ws[4];
    const int lane = t & 63, wv = t >> 6;
    if (lane == 0) ws[wv] = s;
    __syncthreads();
    if (t == 0) sq[row] = ws[0] + ws[1] + ws[2] + ws[3];
}

// Kernel 2: per upper-triangular 64x64 tile pair (ti<=tj): gram via
// MX-fp8 MFMA (scales = 1.0), fused loss epilogue, block reduce, atomicAdd.
__global__ __launch_bounds__(THREADS, 5) void loss_kernel(const uint8_t* __restrict__ Xf8,
                                                          const float* __restrict__ sq,
                                                          const int* __restrict__ labels,
                                                          float* __restrict__ out) {
    __shared__ __align__(16) uint8_t At[2][TILE * BK];   // 2 x 8 KB
    __shared__ __align__(16) uint8_t Bt[2][TILE * BK];   // 2 x 8 KB
    __shared__ float bsum[4];

    // T1: bijective XCD swizzle (2080 % 8 == 0).
    const int b0 = blockIdx.x;
    const int b = (b0 & 7) * (NPAIR / 8) + (b0 >> 3);

    // decode upper-triangular (ti, tj), ti <= tj
    int ti = 0, rem = b;
    while (rem >= NT - ti) { rem -= NT - ti; ++ti; }
    const int tj = ti + rem;

    const int t = threadIdx.x;
    const int lane = t & 63;
    const int wave = t >> 6;      // 0..3
    const int wr = wave >> 1;     // 0..1 : 32-row band of A
    const int wc = wave & 1;      // 0..1 : 32-col band of B
    const int fr = lane & 15;
    const int kg = lane >> 4;

    // Staging: per tile per step = 8 KB = 512 x 16B chunks; 2 insts x 256
    // threads per tile. Chunk p = i*256+t -> row p>>3, chunk p&7; T2 swizzle
    // via pre-swizzled source (rule #21): src chunk = (p&7) ^ (row&7).
    size_t srcA[2], srcB[2];
    int ldst[2];
#pragma unroll
    for (int i = 0; i < 2; ++i) {
        const int p = i * 256 + t;
        const int row = p >> 3;
        const int sc = ((p & 7) ^ (row & 7)) << 4;
        srcA[i] = (size_t)(ti * TILE + row) * DIM + sc;
        srcB[i] = (size_t)(tj * TILE + row) * DIM + sc;
        ldst[i] = p << 4;
    }

    // Read-side swizzled chunk offsets: frag row = band*32 + m*16 + fr
    // -> row&7 == fr&7. Lane k-bytes [kg*32, kg*32+32) = chunks 2kg, 2kg+1.
    const int swz0 = (((kg << 1) ^ (fr & 7)) << 4);
    const int swz1 = swz0 ^ 16;
    const int rbA = (wr * 32 + fr) * BK;
    const int rbB = (wc * 32 + fr) * BK;

    // Diagonal blocks: wave (1,0) fully below diagonal -> skip compute.
    const bool skipw = (ti == tj) && (wr == 1) && (wc == 0);

    f32x4 acc[2][2] = {};

#define STAGE(buf, kt) do {                                            \
        const int _ko = (kt) * BK;                                     \
        _Pragma("unroll")                                              \
        for (int i = 0; i < 2; ++i) {                                  \
            gload_lds16(Xf8 + srcA[i] + _ko, &At[buf][ldst[i]]);       \
            gload_lds16(Xf8 + srcB[i] + _ko, &Bt[buf][ldst[i]]);       \
        }                                                              \
    } while (0)

    int cur = 0;
    STAGE(0, 0);
    __syncthreads();   // drain prologue stage

    for (int kt = 0; kt < KSTEPS; ++kt) {
        if (kt + 1 < KSTEPS) STAGE(cur ^ 1, kt + 1);   // prefetch next tile
        if (!skipw) {
            i32x8 af[2], bv[2];
#pragma unroll
            for (int m = 0; m < 2; ++m) {
                const i32x4 lo = *(const i32x4*)&At[cur][rbA + m * 16 * BK + swz0];
                const i32x4 hi = *(const i32x4*)&At[cur][rbA + m * 16 * BK + swz1];
                af[m][0] = lo[0]; af[m][1] = lo[1]; af[m][2] = lo[2]; af[m][3] = lo[3];
                af[m][4] = hi[0]; af[m][5] = hi[1]; af[m][6] = hi[2]; af[m][7] = hi[3];
            }
#pragma unroll
            for (int n = 0; n < 2; ++n) {
                const i32x4 lo = *(const i32x4*)&Bt[cur][rbB + n * 16 * BK + swz0];
                const i32x4 hi = *(const i32x4*)&Bt[cur][rbB + n * 16 * BK + swz1];
                bv[n][0] = lo[0]; bv[n][1] = lo[1]; bv[n][2] = lo[2]; bv[n][3] = lo[3];
                bv[n][4] = hi[0]; bv[n][5] = hi[1]; bv[n][6] = hi[2]; bv[n][7] = hi[3];
            }
#pragma unroll
            for (int m = 0; m < 2; ++m)
#pragma unroll
                for (int n = 0; n < 2; ++n)
                    acc[m][n] = __builtin_amdgcn_mfma_scale_f32_16x16x128_f8f6f4(
                        af[m], bv[n], acc[m][n],
                        0 /*A=fp8*/, 0 /*B=fp8*/,
                        0, 0x7f7f7f7f,   // scale A = 2^0
                        0, 0x7f7f7f7f);  // scale B = 2^0
        }
        __syncthreads();   // prefetch complete + all reads of cur done
        cur ^= 1;
    }
#undef STAGE

    // epilogue: C/D layout col = lane&15 (=fr), row = kg*4 + q  [m89/m91;
    // shape-determined, dtype-independent per m121-m128]
    int gi[8]; float sqi[8]; int li[8];
#pragma unroll
    for (int m = 0; m < 2; ++m)
#pragma unroll
        for (int q = 0; q < 4; ++q) {
            const int i = ti * TILE + wr * 32 + m * 16 + kg * 4 + q;
            gi[m * 4 + q] = i;
            sqi[m * 4 + q] = sq[i];
            li[m * 4 + q] = labels[i];
        }
    int gj[2]; float sqj[2]; int lj[2];
#pragma unroll
    for (int n = 0; n < 2; ++n) {
        const int j = tj * TILE + wc * 32 + n * 16 + fr;
        gj[n] = j;
        sqj[n] = sq[j];
        lj[n] = labels[j];
    }

    const float coeff = 2047.0f;                        // N/2 - 1
    const float inva = 1.0f / (2.0f * 4096.0f * 0.04f); // 1/327.68
    const float invb = 1.0f / (2.0f * 4096.0f);         // 1/8192
    const float lc1 = -5.792037522411088f;              // ln(inva)
    const float lc2 = -9.010913347279289f;              // ln(invb)
    const bool diag = (ti == tj);

    float lsum = 0.0f;
#pragma unroll
    for (int m = 0; m < 2; ++m)
#pragma unroll
        for (int n = 0; n < 2; ++n)
#pragma unroll
            for (int q = 0; q < 4; ++q) {
                const int ii = m * 4 + q;
                const float g = acc[m][n][q];
                float d2 = sqi[ii] + sqj[n] - 2.0f * g;
                d2 = fmaxf(d2, 1e-12f);
                const bool same = (li[ii] == lj[n]);
                const float inv = same ? inva : invb;
                const float lc  = same ? lc1 : lc2;
                const float sgn = same ? -1.0f : 1.0f;
                const float p = sgn * (coeff * (__logf(d2) + lc) - 0.5f * d2 * inv);
                const bool inc = diag ? (gi[ii] < gj[n]) : true;
                lsum += inc ? p : 0.0f;
            }

    // block reduce + one atomic per block
#pragma unroll
    for (int off = 32; off > 0; off >>= 1) lsum += __shfl_down(lsum, off);
    if (lane == 0) bsum[wave] = lsum;
    __syncthreads();
    if (t == 0) atomicAdd(out, bsum[0] + bsum[1] + bsum[2] + bsum[3]);
}

extern "C" void kernel_launch(void* const* d_in, const int* in_sizes, int n_in,
                              void* d_out, int out_size, void* d_ws, size_t ws_size,
                              hipStream_t stream) {
    const float* X = (const float*)d_in[0];
    const int* labels = (const int*)d_in[1];
    float* out = (float*)d_out;
    uint8_t* Xf8 = (uint8_t*)d_ws;                                  // 4 MB fp8
    float* sq = (float*)((char*)d_ws + (size_t)NPTS * DIM);         // 16 KB

    prep_kernel<<<NPTS, 256, 0, stream>>>(X, Xf8, sq, out);
    loss_kernel<<<NPAIR, THREADS, 0, stream>>>(Xf8, sq, labels, out);
}

// Round 10
// 92.843 us; speedup vs baseline: 1.2717x; 1.1126x over previous
//
#include <hip/hip_runtime.h>
#include <hip/hip_bf16.h>
#include <stdint.h>

// MetricLearningLoss: N=4096 points, D=1024, fp32 inputs, int labels.
// loss = sum_{i<j} [ same: -coeff*log(a)+0.5a ; diff: coeff*log(b)-0.5b ]
// R10: T4 counted-vmcnt schedule on R4's base (128^2 tile, BK=128 MX-fp8,
// 4 waves, dbuf). Raw s_barrier + hand-counted s_waitcnt: vmcnt(8) keeps
// the next stage's 8 global_load_lds in flight ACROSS barriers (never
// drain to 0 in the loop, m218). Step order: ds_read -> lgkmcnt(0)+bar ->
// stage(kt+2) into just-read buf -> setprio-MFMA -> vmcnt(8)+bar.
// T1 XCD swizzle, T2 swizzle via pre-swizzled source, diag-wave skip.

#define NPTS 4096
#define DIM  1024
#define TILE 128
#define BK   128                      // fp8 bytes (= elems) per k-step
#define KSTEPS (DIM / BK)             // 8
#define NT   (NPTS / TILE)            // 32
#define NPAIR (NT * (NT + 1) / 2)     // 528 = 8 * 66
#define THREADS 256

typedef __attribute__((ext_vector_type(4))) float f32x4;
typedef __attribute__((ext_vector_type(4))) int   i32x4;
typedef __attribute__((ext_vector_type(8))) int   i32x8;

#define WAITV8 asm volatile("s_waitcnt vmcnt(8)" ::: "memory")
#define WAITV0 asm volatile("s_waitcnt vmcnt(0)" ::: "memory")
#define WAITL0 asm volatile("s_waitcnt lgkmcnt(0)" ::: "memory")
#define SCHEDB __builtin_amdgcn_sched_barrier(0)
#define SBAR   __builtin_amdgcn_s_barrier()

__device__ __forceinline__ void gload_lds16(const void* g, void* l) {
    __builtin_amdgcn_global_load_lds(
        (const __attribute__((address_space(1))) void*)g,
        (__attribute__((address_space(3))) void*)l, 16, 0, 0);
}

// Kernel 1: fp32 -> fp8 e4m3 (OCP, native gfx950 cvt) + per-row sum of
// squares in fp32 (exact norms; only the gram term is quantized).
// Also zeroes the output scalar (replaces a separate memset dispatch).
__global__ __launch_bounds__(256) void prep_kernel(const float* __restrict__ X,
                                                   uint8_t* __restrict__ Xf8,
                                                   float* __restrict__ sq,
                                                   float* __restrict__ out) {
    const int row = blockIdx.x;
    const int t = threadIdx.x;
    if (row == 0 && t == 0) out[0] = 0.0f;   // stream-ordered before loss_kernel
    const float4 v = reinterpret_cast<const float4*>(X + (size_t)row * DIM)[t];
    float s = v.x * v.x + v.y * v.y + v.z * v.z + v.w * v.w;
    int w = __builtin_amdgcn_cvt_pk_fp8_f32(v.x, v.y, 0, false);
    w = __builtin_amdgcn_cvt_pk_fp8_f32(v.z, v.w, w, true);
    reinterpret_cast<int*>(Xf8 + (size_t)row * DIM)[t] = w;
#pragma unroll
    for (int off = 32; off > 0; off >>= 1) s += __shfl_down(s, off);
    __shared__ float ws[4];
    const int lane = t & 63, wv = t >> 6;
    if (lane == 0) ws[wv] = s;
    __syncthreads();
    if (t == 0) sq[row] = ws[0] + ws[1] + ws[2] + ws[3];
}

// Kernel 2: per upper-triangular 128x128 tile pair (ti<=tj): gram via
// MX-fp8 MFMA (scales = 1.0), counted-vmcnt pipeline, fused loss
// epilogue, block reduce, atomicAdd.
__global__ __launch_bounds__(THREADS, 2) void loss_kernel(const uint8_t* __restrict__ Xf8,
                                                          const float* __restrict__ sq,
                                                          const int* __restrict__ labels,
                                                          float* __restrict__ out) {
    __shared__ __align__(16) uint8_t At[2][TILE * BK];   // 2 x 16 KB
    __shared__ __align__(16) uint8_t Bt[2][TILE * BK];   // 2 x 16 KB
    __shared__ float bsum[4];

    // T1: bijective XCD swizzle (528 % 8 == 0).
    const int b0 = blockIdx.x;
    const int b = (b0 & 7) * (NPAIR / 8) + (b0 >> 3);

    // decode upper-triangular (ti, tj), ti <= tj
    int ti = 0, rem = b;
    while (rem >= NT - ti) { rem -= NT - ti; ++ti; }
    const int tj = ti + rem;

    const int t = threadIdx.x;
    const int lane = t & 63;
    const int wave = t >> 6;      // 0..3
    const int wr = wave >> 1;     // 0..1 : 64-row band of A
    const int wc = wave & 1;      // 0..1 : 64-col band of B
    const int fr = lane & 15;
    const int kg = lane >> 4;

    // Staging: per tile per step = 16 KB = 1024 x 16B chunks; 4 insts x 256
    // threads. Chunk p = i*256+t -> row p>>3, chunk p&7; T2 swizzle via
    // pre-swizzled source (rule #21): src chunk = (p&7) ^ (row&7).
    size_t srcA[4], srcB[4];
    int ldst[4];
#pragma unroll
    for (int i = 0; i < 4; ++i) {
        const int p = i * 256 + t;
        const int row = p >> 3;
        const int sc = ((p & 7) ^ (row & 7)) << 4;
        srcA[i] = (size_t)(ti * TILE + row) * DIM + sc;
        srcB[i] = (size_t)(tj * TILE + row) * DIM + sc;
        ldst[i] = p << 4;
    }

    // Read-side swizzled chunk offsets (frag row = band + m*16 + fr ->
    // row&7 == fr&7). Lane k-bytes [kg*32, kg*32+32) = chunks 2kg, 2kg+1.
    const int swz0 = (((kg << 1) ^ (fr & 7)) << 4);
    const int swz1 = swz0 ^ 16;
    const int rbA = (wr * 64 + fr) * BK;
    const int rbB = (wc * 64 + fr) * BK;

    // Diagonal blocks: wave (1,0) fully below diagonal -> skip compute.
    const bool skipw = (ti == tj) && (wr == 1) && (wc == 0);

    f32x4 acc[4][4] = {};

#define STAGE(buf, kt) do {                                            \
        const int _ko = (kt) * BK;                                     \
        _Pragma("unroll")                                              \
        for (int i = 0; i < 4; ++i) {                                  \
            gload_lds16(Xf8 + srcA[i] + _ko, &At[buf][ldst[i]]);       \
            gload_lds16(Xf8 + srcB[i] + _ko, &Bt[buf][ldst[i]]);       \
        }                                                              \
    } while (0)

    // 2-deep prologue: 16 loads in flight; wait only for stage 0 (8 left).
    STAGE(0, 0);
    STAGE(1, 1);
    WAITV8; SCHEDB; SBAR;

    int cur = 0;
#pragma unroll
    for (int kt = 0; kt < KSTEPS; ++kt) {
        i32x8 af[4], bv[4];
        if (!skipw) {
#pragma unroll
            for (int m = 0; m < 4; ++m) {
                const i32x4 lo = *(const i32x4*)&At[cur][rbA + m * 16 * BK + swz0];
                const i32x4 hi = *(const i32x4*)&At[cur][rbA + m * 16 * BK + swz1];
                af[m][0] = lo[0]; af[m][1] = lo[1]; af[m][2] = lo[2]; af[m][3] = lo[3];
                af[m][4] = hi[0]; af[m][5] = hi[1]; af[m][6] = hi[2]; af[m][7] = hi[3];
            }
#pragma unroll
            for (int n = 0; n < 4; ++n) {
                const i32x4 lo = *(const i32x4*)&Bt[cur][rbB + n * 16 * BK + swz0];
                const i32x4 hi = *(const i32x4*)&Bt[cur][rbB + n * 16 * BK + swz1];
                bv[n][0] = lo[0]; bv[n][1] = lo[1]; bv[n][2] = lo[2]; bv[n][3] = lo[3];
                bv[n][4] = hi[0]; bv[n][5] = hi[1]; bv[n][6] = hi[2]; bv[n][7] = hi[3];
            }
        }
        // All waves' reads of buf[cur] complete -> safe to overwrite it.
        WAITL0; SCHEDB; SBAR;
        if (kt + 2 < KSTEPS) STAGE(cur, kt + 2);   // refill just-read buffer
        if (!skipw) {
            __builtin_amdgcn_s_setprio(1);
#pragma unroll
            for (int m = 0; m < 4; ++m)
#pragma unroll
                for (int n = 0; n < 4; ++n)
                    acc[m][n] = __builtin_amdgcn_mfma_scale_f32_16x16x128_f8f6f4(
                        af[m], bv[n], acc[m][n],
                        0 /*A=fp8*/, 0 /*B=fp8*/,
                        0, 0x7f7f7f7f,   // scale A = 2^0
                        0, 0x7f7f7f7f);  // scale B = 2^0
            __builtin_amdgcn_s_setprio(0);
        }
        // Counted drain: stage(kt+1) complete, stage(kt+2)'s 8 stay in flight.
        if (kt < KSTEPS - 2)       { WAITV8; SCHEDB; SBAR; }
        else if (kt == KSTEPS - 2) { WAITV0; SCHEDB; SBAR; }
        // kt == KSTEPS-1: no further LDS use; fall through to epilogue.
        cur ^= 1;
    }
#undef STAGE

    // epilogue: C/D layout col = lane&15 (=fr), row = kg*4 + q  [m89/m91;
    // shape-determined, dtype-independent per m121-m128]
    int gi[16]; float sqi[16]; int li[16];
#pragma unroll
    for (int m = 0; m < 4; ++m)
#pragma unroll
        for (int q = 0; q < 4; ++q) {
            const int i = ti * TILE + wr * 64 + m * 16 + kg * 4 + q;
            gi[m * 4 + q] = i;
            sqi[m * 4 + q] = sq[i];
            li[m * 4 + q] = labels[i];
        }
    int gj[4]; float sqj[4]; int lj[4];
#pragma unroll
    for (int n = 0; n < 4; ++n) {
        const int j = tj * TILE + wc * 64 + n * 16 + fr;
        gj[n] = j;
        sqj[n] = sq[j];
        lj[n] = labels[j];
    }

    const float coeff = 2047.0f;                        // N/2 - 1
    const float inva = 1.0f / (2.0f * 4096.0f * 0.04f); // 1/327.68
    const float invb = 1.0f / (2.0f * 4096.0f);         // 1/8192
    const float lc1 = -5.792037522411088f;              // ln(inva)
    const float lc2 = -9.010913347279289f;              // ln(invb)
    const bool diag = (ti == tj);

    float lsum = 0.0f;
#pragma unroll
    for (int m = 0; m < 4; ++m)
#pragma unroll
        for (int n = 0; n < 4; ++n)
#pragma unroll
            for (int q = 0; q < 4; ++q) {
                const int ii = m * 4 + q;
                const float g = acc[m][n][q];
                float d2 = sqi[ii] + sqj[n] - 2.0f * g;
                d2 = fmaxf(d2, 1e-12f);
                const bool same = (li[ii] == lj[n]);
                const float inv = same ? inva : invb;
                const float lc  = same ? lc1 : lc2;
                const float sgn = same ? -1.0f : 1.0f;
                const float p = sgn * (coeff * (__logf(d2) + lc) - 0.5f * d2 * inv);
                const bool inc = diag ? (gi[ii] < gj[n]) : true;
                lsum += inc ? p : 0.0f;
            }

    // block reduce + one atomic per block
#pragma unroll
    for (int off = 32; off > 0; off >>= 1) lsum += __shfl_down(lsum, off);
    if (lane == 0) bsum[wave] = lsum;
    __syncthreads();
    if (t == 0) atomicAdd(out, bsum[0] + bsum[1] + bsum[2] + bsum[3]);
}

extern "C" void kernel_launch(void* const* d_in, const int* in_sizes, int n_in,
                              void* d_out, int out_size, void* d_ws, size_t ws_size,
                              hipStream_t stream) {
    const float* X = (const float*)d_in[0];
    const int* labels = (const int*)d_in[1];
    float* out = (float*)d_out;
    uint8_t* Xf8 = (uint8_t*)d_ws;                                  // 4 MB fp8
    float* sq = (float*)((char*)d_ws + (size_t)NPTS * DIM);         // 16 KB

    prep_kernel<<<NPTS, 256, 0, stream>>>(X, Xf8, sq, out);
    loss_kernel<<<NPAIR, THREADS, 0, stream>>>(Xf8, sq, labels, out);
}